// Round 17
// baseline (674.158 us; speedup 1.0000x reference)
//
#include <hip/hip_runtime.h>
#include <stdint.h>

#define NSUP   50000
#define NSUPP  50176      // 392 * 128
#define NQRY   2048
#define KD     512
#define NKT    16         // K tiles of 32
#define NQT    16         // query tiles of 128

typedef __attribute__((ext_vector_type(8))) short bf16x8;
typedef __attribute__((ext_vector_type(4))) float f32x4;

__device__ __forceinline__ unsigned short f2bf(float f) {
  unsigned int u = __float_as_uint(f);
  u += 0x7FFFu + ((u >> 16) & 1u);   // round-to-nearest-even
  return (unsigned short)(u >> 16);
}

// ---- prep: fused norm + normalize + f32->bf16 ----
// Support rows -> s_bf row-major (pad rows zeroed).
// Query rows  -> Qf in MFMA-fragment order: fragment (q16,kt) holds
// element (lane,j) = Qn[q16*16 + (lane&15)][kt*32 + (lane>>4)*8 + j]
// at Qf[((q16*16+kt)*64 + lane)*8 + j]. A wave's B-frag load is then one
// coalesced 1KB global_load_dwordx4, L2-resident (2 MB total).
__global__ __launch_bounds__(256) void prep_kernel(
    const float* __restrict__ sup, const float* __restrict__ qry,
    unsigned short* __restrict__ s_bf, unsigned short* __restrict__ Qf) {
  const int row  = blockIdx.x * 4 + (threadIdx.x >> 6);
  const int lane = threadIdx.x & 63;

  const float* src = nullptr;
  bool is_q = false;
  int q = 0;
  if (row < NSUPP) {
    if (row < NSUP) src = sup + (size_t)row * KD;
  } else {
    q = row - NSUPP;
    src = qry + (size_t)q * KD;
    is_q = true;
  }

  if (src == nullptr) {           // zero pad support row
    bf16x8 z = {};
    *(bf16x8*)(s_bf + (size_t)row * KD + lane * 8) = z;
    return;
  }

  const float4 v0 = ((const float4*)src)[lane * 2 + 0];
  const float4 v1 = ((const float4*)src)[lane * 2 + 1];
  float ss = v0.x*v0.x + v0.y*v0.y + v0.z*v0.z + v0.w*v0.w
           + v1.x*v1.x + v1.y*v1.y + v1.z*v1.z + v1.w*v1.w;
  #pragma unroll
  for (int off = 32; off > 0; off >>= 1) ss += __shfl_xor(ss, off);
  const float inv = rsqrtf(fmaxf(ss, 1e-30f));

  bf16x8 o;
  o[0]=(short)f2bf(v0.x*inv); o[1]=(short)f2bf(v0.y*inv);
  o[2]=(short)f2bf(v0.z*inv); o[3]=(short)f2bf(v0.w*inv);
  o[4]=(short)f2bf(v1.x*inv); o[5]=(short)f2bf(v1.y*inv);
  o[6]=(short)f2bf(v1.z*inv); o[7]=(short)f2bf(v1.w*inv);

  if (!is_q) {
    *(bf16x8*)(s_bf + (size_t)row * KD + lane * 8) = o;
  } else {
    // lane covers k = lane*8..lane*8+7  ->  kt = lane>>2, hi = lane&3
    const int q16 = q >> 4, rq = q & 15;
    const int kt = lane >> 2, hi = lane & 3;
    const int ldst = hi * 16 + rq;
    *(bf16x8*)(Qf + ((size_t)(q16 * 16 + kt) * 64 + ldst) * 8) = o;
  }
}

// ---- GEMM: out[q][s] = dot(qn[q], sn[s])  (inputs pre-normalized) ----
// One block per 128-support stile; whole stile (128x512 bf16 = 131 KB)
// resident in dynamic LDS -> S fetched from HBM exactly ONCE by
// construction (no L2/XCD assumptions). 512 threads / 8 waves (2 S-halves
// x 4 Q-quarters). Block sweeps 16 qtiles x 16 ktiles; B-frags stream
// from Qf (L2-hot, coalesced); K-loop is BARRIER-FREE (S-LDS read-only).
// LDS granule swizzle: LDS[row][g] = global[row][g ^ (row&7)] (16B units)
// -> frag reads 2-way banked = free; staged via inverse-permuted source.
__global__ __launch_bounds__(512, 1) void gemm_kernel(
    const unsigned short* __restrict__ S,    // [NSUPP][KD] normalized bf16
    const unsigned short* __restrict__ Qf,   // fragment-ordered queries
    float* __restrict__ out) {               // [NQRY][NSUP]
  extern __shared__ unsigned short Sl[];     // 128 * 512 = 131072 B

  const int tid = threadIdx.x;
  const int w = tid >> 6, l = tid & 63;
  const int wr = w >> 2, wn = w & 3;         // wave -> (S half, Q quarter)
  const int rof = l & 15, hi = l >> 4;
  const int ts = blockIdx.x * 128;

  // prologue: stage the whole stile. wave w stages row i*8+w (1024 B = 64
  // lanes x 16 B); source granule l^w realizes the LDS swizzle.
  #pragma unroll
  for (int i = 0; i < 16; ++i) {
    const int row = i * 8 + w;
    const unsigned short* src = S + (size_t)(ts + row) * KD + ((l ^ w) * 8);
    unsigned short* dst = Sl + row * KD + l * 8;
    __builtin_amdgcn_global_load_lds(
        (const __attribute__((address_space(1))) void*)src,
        (__attribute__((address_space(3))) void*)dst, 16, 0, 0);
  }
  __syncthreads();   // drains vmcnt; the only barrier in the kernel

  #pragma unroll 1
  for (int qt = 0; qt < NQT; ++qt) {
    f32x4 acc[4][2] = {};

    #pragma unroll
    for (int kt = 0; kt < NKT; ++kt) {
      bf16x8 b[2];
      #pragma unroll
      for (int i = 0; i < 2; ++i) {
        const int q16 = qt * 8 + wn * 2 + i;
        b[i] = *(const bf16x8*)(Qf + ((size_t)(q16 * 16 + kt) * 64 + l) * 8);
      }
      bf16x8 a[4];
      #pragma unroll
      for (int i = 0; i < 4; ++i) {
        const int R = wr * 64 + i * 16 + rof;
        const int g = (kt * 4 + hi) ^ (R & 7);
        a[i] = *(const bf16x8*)(Sl + R * KD + g * 8);
      }
      #pragma unroll
      for (int mi = 0; mi < 4; ++mi)
        #pragma unroll
        for (int ni = 0; ni < 2; ++ni)
          acc[mi][ni] = __builtin_amdgcn_mfma_f32_16x16x32_bf16(a[mi], b[ni], acc[mi][ni], 0, 0, 0);
    }

    // epilogue: nt dwordx4 stores (output never re-read; keep L2 clean)
    #pragma unroll
    for (int mi = 0; mi < 4; ++mi) {
      const int s = ts + wr * 64 + mi * 16 + hi * 4;
      if (s < NSUP) {                        // s%4==0, NSUP%4==0 -> all-or-none
        #pragma unroll
        for (int ni = 0; ni < 2; ++ni) {
          const int q = qt * 128 + wn * 32 + ni * 16 + rof;
          __builtin_nontemporal_store(acc[mi][ni],
                                      (f32x4*)(out + (size_t)q * NSUP + s));
        }
      }
    }
  }
}

extern "C" void kernel_launch(void* const* d_in, const int* in_sizes, int n_in,
                              void* d_out, int out_size, void* d_ws, size_t ws_size,
                              hipStream_t stream) {
  const float* sup = (const float*)d_in[0];   // [50000][512] f32
  const float* qry = (const float*)d_in[1];   // [2048][512] f32
  float* out = (float*)d_out;                 // [2048][50000] f32

  char* ws = (char*)d_ws;
  unsigned short* s_bf = (unsigned short*)(ws);
  unsigned short* Qf   = (unsigned short*)(ws + (size_t)NSUPP * KD * 2);
  // ws use: 50176*512*2 + 2048*512*2 = 53.5 MB

  prep_kernel<<<(NSUPP + NQRY) / 4, 256, 0, stream>>>(sup, qry, s_bf, Qf);

  gemm_kernel<<<392, 512, 131072, stream>>>(s_bf, Qf, out);
}